// Round 8
// baseline (3332.284 us; speedup 1.0000x reference)
//
#include <hip/hip_runtime.h>
#include <math.h>

// Problem dims
#define S_LEN  512
#define BATCH  64
#define E_DIM  512
#define H_DIM  512
#define G4     2048          // 4*H
#define VOCAB  32000
#define NWG    16            // persistent LSTM workgroups (1 per 16 CUs; trivially co-resident)

typedef int v4i __attribute__((ext_vector_type(4)));
typedef unsigned long long u64;

// Workspace layout (bytes). Total ~19.0 MiB.
// O_FLG: publish flags [2 slots][4 wv][16 g] u32 — one 64B line per (slot,wv).
// h exchange: 2 slots x 64 batches x 64 units x 16B ({8 codes, 4B tag, 4B pad})
#define O_BAR   0                         // legacy/unused (memset-covered)
#define O_FLG   256                       // 512 B publish flags
#define O_MAX   768                       // 4 uints: maxabs emb, ih, hh, fc
#define O_H8    1024                      // 2 * 65536 B tagged h units
#define O_FC8   (O_H8 + 131072)           // 1024 int8
#define O_WIH8  (O_FC8 + 1024)            // 2048*512 int8 (1 MiB)
#define O_WHH8  (O_WIH8 + 1048576)
#define O_X8    (O_WHH8 + 1048576)        // 512*64*512 int8 (16 MiB), t-major

__device__ __forceinline__ float clampf(float x, float lo, float hi) {
    return fminf(fmaxf(x, lo), hi);
}

// k = ceil(log2(maxabs/127)) via frexp (exact, no transcendental)
__device__ __forceinline__ int scale_exp(float maxabs) {
    double t = (double)maxabs / 127.0;
    int e; double f = frexp(t, &e);
    return (f == 0.5) ? (e - 1) : e;
}

// ---- XLA-CPU / Eigen fast tanh (f32), bit-exact vs the jax-CPU golden ------
__device__ __forceinline__ float xla_tanhf(float x) {
    if (fabsf(x) < 0.0004f) return x;
    float xc = fminf(fmaxf(x, -7.90531110763549805f), 7.90531110763549805f);
    float x2 = __fmul_rn(xc, xc);
    float p = fmaf(x2, -2.76076847742355e-16f, 2.00018790482477e-13f);
    p = fmaf(x2, p, -8.60467152213735e-11f);
    p = fmaf(x2, p, 5.12229709037114e-08f);
    p = fmaf(x2, p, 1.48572235717979e-05f);
    p = fmaf(x2, p, 6.37261928875436e-04f);
    p = fmaf(x2, p, 4.89352455891786e-03f);
    p = __fmul_rn(xc, p);
    float q = fmaf(x2, 1.19825839466702e-06f, 1.18534705686654e-04f);
    q = fmaf(x2, q, 2.26843463243900e-03f);
    q = fmaf(x2, q, 4.89352518554385e-03f);
    return __fdiv_rn(p, q);
}

// ---------------- maxabs reduction ----------------
__global__ void k_maxabs(const float* __restrict__ x, int n, unsigned* __restrict__ out) {
    unsigned m = 0;
    for (int i = blockIdx.x * blockDim.x + threadIdx.x; i < n; i += gridDim.x * blockDim.x)
        m = max(m, __float_as_uint(fabsf(x[i])));
    #pragma unroll
    for (int o = 32; o > 0; o >>= 1) {
        unsigned other = (unsigned)__shfl_down((int)m, o, 64);
        m = max(m, other);
    }
    __shared__ unsigned sm[4];
    if ((threadIdx.x & 63) == 0) sm[threadIdx.x >> 6] = m;
    __syncthreads();
    if (threadIdx.x == 0) {
        unsigned r = sm[0];
        for (int w = 1; w < (int)(blockDim.x >> 6); w++) r = max(r, sm[w]);
        atomicMax(out, r);
    }
}

// ---------------- weight quantization (exact: pow2 scale) ----------------
__global__ void k_quantw(const float* __restrict__ w, int n, const unsigned* __restrict__ mx,
                         signed char* __restrict__ q) {
    float inv = ldexpf(1.0f, -scale_exp(__uint_as_float(*mx)));
    for (int i = blockIdx.x * blockDim.x + threadIdx.x; i < n; i += gridDim.x * blockDim.x) {
        float v = clampf(rintf(w[i] * inv), -128.0f, 127.0f);
        q[i] = (signed char)(int)v;
    }
}

// ---------------- embedding lookup + double quantization (exact: pow2 scales) ----
__global__ void k_embed(const float* __restrict__ emb, const int* __restrict__ text,
                        const unsigned* __restrict__ mx, signed char* __restrict__ x8) {
    int row = blockIdx.x;                       // b*S + s (text is [B,S] row-major)
    int b = row >> 9, s = row & 511;
    int tok = text[row];
    int ke = scale_exp(__uint_as_float(*mx));
    float inv = ldexpf(1.0f, -ke);
    float sc2 = ldexpf(1.0f, ke + 4);
    const float4* src = (const float4*)(emb + (size_t)tok * E_DIM);
    char4* dst = (char4*)(x8 + (size_t)(s * BATCH + b) * E_DIM);
    float4 v = src[threadIdx.x];
    char4 c;
    float q;
    q = clampf(rintf(v.x * inv), -128.f, 127.f); c.x = (signed char)(int)clampf(rintf(q * sc2), -128.f, 127.f);
    q = clampf(rintf(v.y * inv), -128.f, 127.f); c.y = (signed char)(int)clampf(rintf(q * sc2), -128.f, 127.f);
    q = clampf(rintf(v.z * inv), -128.f, 127.f); c.z = (signed char)(int)clampf(rintf(q * sc2), -128.f, 127.f);
    q = clampf(rintf(v.w * inv), -128.f, 127.f); c.w = (signed char)(int)clampf(rintf(q * sc2), -128.f, 127.f);
    dst[threadIdx.x] = c;
}

// ---------------- persistent fused LSTM, barrier-free tagged dataflow ----------
// R8: ATOMIC read path. Seven experiments showed the ~10k-cy/step wait is
// read-side: re-reading the same address until it changes is served by a
// lazily-updated cached copy — insensitive to store draining (R7), read
// traffic (R5), replication (R4), flags via plain loads (R3), L2 locality
// (R2/R6). Atomic RMWs execute AT the coherence point (TCC) and cannot hit a
// stale copy [m20, G16] — the one untested mechanism. Changes vs baseline:
//   consumer: spin on per-wave flags via atomic_fetch_add(0) (16 lanes, one
//             64B line), then read h codes via 16x u64 atomic_fetch_add(0);
//   producer: tagged 16B stores (unchanged) -> s_waitcnt vmcnt(0) (at
//             coherence point, R7-verified) -> lane0 atomic_exchange(flag,t+1).
// Ordering: flag t+1 observed => that wave's drained stores are at TCC =>
// atomic reads see them. Slot-reuse safety: identical row-partitioned
// symmetry argument as baseline (flag wait <=> tag wait). Numerics frozen.
__global__ __launch_bounds__(256, 1) void k_lstm(
    const signed char* __restrict__ wih8, const signed char* __restrict__ whh8,
    const signed char* __restrict__ x8, const float* __restrict__ b_ih,
    const float* __restrict__ b_hh, const unsigned* __restrict__ mx,
    signed char* __restrict__ h8, unsigned* __restrict__ flg) {
    __shared__ __attribute__((aligned(16))) signed char wih_lds[128 * 528]; // rows padded 512->528
    __shared__ __attribute__((aligned(16))) signed char hstage[BATCH * 32]; // [b][jloc] codes
    __shared__ float lut_sig[256];
    __shared__ float lut_tnh[256];

    const int g = blockIdx.x;
    const int tid = threadIdx.x;
    const int wv = tid >> 6, lane = tid & 63, l15 = lane & 15, qd4 = lane >> 4;
    const float sih = ldexpf(1.0f, scale_exp(__uint_as_float(mx[1])) - 4);
    const float shh = ldexpf(1.0f, scale_exp(__uint_as_float(mx[2])) - 4);

    // Gate LUTs via XLA formulas (bit-exact policy from R6)
    if (tid < 256) {
        float v = (float)(tid - 128) * 0.125f;
        float sg = __fadd_rn(0.5f, __fmul_rn(0.5f, xla_tanhf(__fmul_rn(0.5f, v))));
        float sc = clampf(rintf(__fmul_rn(sg, 256.0f)), 0.0f, 255.0f);
        lut_sig[tid] = sc * 0.00390625f;
        float th = xla_tanhf(v);
        float tc = clampf(rintf(__fmul_rn(th, 128.0f)), -128.0f, 127.0f);
        lut_tnh[tid] = tc * 0.0078125f;
    }

    // Stage wih slice into LDS (used only by the prefetch GEMM)
    for (int it = 0; it < 16; it++) {
        int idx = it * 256 + tid;               // 16B chunks
        int r = idx >> 5, cc = (idx & 31) * 16;
        int grow = (r >> 5) * 512 + g * 32 + (r & 31);
        *(v4i*)(wih_lds + r * 528 + cc) = *(const v4i*)(wih8 + (size_t)grow * 512 + cc);
    }

    // whh slice fragments -> registers (64 x v4i; 1 wave/SIMD by design)
    v4i whf[8][8];
    #pragma unroll
    for (int nt = 0; nt < 8; nt++) {
        int nl = nt * 16 + l15;
        size_t grow = (size_t)((nl >> 5) * 512 + g * 32 + (nl & 31)) * 512;
        #pragma unroll
        for (int k = 0; k < 8; k++)
            whf[nt][k] = *(const v4i*)(whh8 + grow + k * 64 + qd4 * 16);
    }
    __syncthreads();   // LUTs + wih_lds ready (the ONLY workgroup barrier)

    // per-lane biases for the 8 N-tiles
    float bi[8], bh[8];
    #pragma unroll
    for (int nt = 0; nt < 8; nt++) {
        int nl = nt * 16 + l15;
        int col = (nl >> 5) * 512 + g * 32 + (nl & 31);
        bi[nt] = b_ih[col];
        bh[nt] = b_hh[col];
    }

    float cst[2][4];
    #pragma unroll
    for (int jh = 0; jh < 2; jh++)
        #pragma unroll
        for (int r = 0; r < 4; r++) cst[jh][r] = 0.0f;

    // input-gate accumulators for the CURRENT step (step 0 preloop)
    v4i xacc[8];
    {
        v4i xfr[8];
        const signed char* xrow = x8 + (size_t)(wv * 16 + l15) * 512 + qd4 * 16;
        #pragma unroll
        for (int k = 0; k < 8; k++) xfr[k] = *(const v4i*)(xrow + k * 64);
        #pragma unroll
        for (int nt = 0; nt < 8; nt++) {
            v4i a = (v4i){0, 0, 0, 0};
            #pragma unroll
            for (int k = 0; k < 8; k++) {
                v4i bf = *(const v4i*)(wih_lds + (nt * 16 + l15) * 528 + k * 64 + qd4 * 16);
                a = __builtin_amdgcn_mfma_i32_16x16x64_i8(xfr[k], bf, a, 0, 0, 0);
            }
            xacc[nt] = a;
        }
    }

    const int row = wv * 16 + l15;                       // this lane's batch row
    const int pb = tid >> 2, psub = tid & 3;             // producer unit: batch, sub
    const u64 paddr_base = (u64)(h8) + (u64)(pb * 64 + g * 4 + psub) * 16;
    const u64 caddr_base = (u64)(h8) + (u64)(row * 64 + qd4 * 2) * 16;
    unsigned* const frd = flg + wv * 16 + l15;           // consumer flag lane addr
    unsigned* const fwr = flg + wv * 16 + g;             // producer flag addr

    for (int t = 0; t < S_LEN; t++) {
        // ---- flag spin: per-wave publish flags, atomic RMW (at-TCC read) ----
        {
            unsigned* fa = frd + (t & 1) * 64;
            for (;;) {
                unsigned fv = __hip_atomic_fetch_add(fa, 0u, __ATOMIC_RELAXED,
                                                     __HIP_MEMORY_SCOPE_SYSTEM);
                if (__all(fv == (unsigned)t)) break;
                __builtin_amdgcn_s_sleep(1);
            }
        }

        // ---- h[t] codes via u64 atomic reads (cannot hit a stale cached copy) ----
        u64 ha = caddr_base + (u64)(t & 1) * 65536;
        u64 c[16];
        #pragma unroll
        for (int k = 0; k < 8; k++) {
            c[2 * k] = __hip_atomic_fetch_add((u64*)(ha + (u64)k * 128), 0ull,
                                              __ATOMIC_RELAXED, __HIP_MEMORY_SCOPE_SYSTEM);
            c[2 * k + 1] = __hip_atomic_fetch_add((u64*)(ha + (u64)k * 128 + 16), 0ull,
                                                  __ATOMIC_RELAXED, __HIP_MEMORY_SCOPE_SYSTEM);
        }
        v4i afr[8];
        #pragma unroll
        for (int i = 0; i < 8; i++)
            afr[i] = (v4i){(int)(c[2 * i] & 0xffffffffu), (int)(c[2 * i] >> 32),
                           (int)(c[2 * i + 1] & 0xffffffffu), (int)(c[2 * i + 1] >> 32)};

        // ---- hh GEMM (reg-resident B) + f32 pre-activations (ref association) ----
        float pre[8][4];
        #pragma unroll
        for (int nt = 0; nt < 8; nt++) {
            v4i hacc = (v4i){0, 0, 0, 0};
            #pragma unroll
            for (int k = 0; k < 8; k++)
                hacc = __builtin_amdgcn_mfma_i32_16x16x64_i8(afr[k], whf[nt][k], hacc, 0, 0, 0);
            #pragma unroll
            for (int r = 0; r < 4; r++)
                pre[nt][r] = __fadd_rn(
                    __fadd_rn(__fadd_rn(__fmul_rn((float)xacc[nt][r], sih), bi[nt]), bh[nt]),
                    __fmul_rn((float)hacc[r], shh));
        }

        // ---- gate math (bit-exact policy); stage h codes into wave-private LDS rows ----
        #pragma unroll
        for (int jh = 0; jh < 2; jh++)
            #pragma unroll
            for (int r = 0; r < 4; r++) {
                int ii = (int)clampf(rintf(__fmul_rn(pre[0 + jh][r], 8.0f)), -128.f, 127.f) + 128;
                int fi = (int)clampf(rintf(__fmul_rn(pre[2 + jh][r], 8.0f)), -128.f, 127.f) + 128;
                int gi = (int)clampf(rintf(__fmul_rn(pre[4 + jh][r], 8.0f)), -128.f, 127.f) + 128;
                int oi = (int)clampf(rintf(__fmul_rn(pre[6 + jh][r], 8.0f)), -128.f, 127.f) + 128;
                float iq = lut_sig[ii], fq = lut_sig[fi], oq = lut_sig[oi];
                float gq = lut_tnh[gi];
                float c2 = __fadd_rn(__fmul_rn(fq, cst[jh][r]), __fmul_rn(iq, gq));
                cst[jh][r] = c2;
                float tc32 = xla_tanhf(c2);
                float tq = clampf(rintf(__fmul_rn(tc32, 128.0f)), -128.f, 127.f) * 0.0078125f;
                float hv = __fmul_rn(oq, tq);
                int hc = (int)clampf(rintf(__fmul_rn(hv, 16.0f)), -128.f, 127.f);
                int b = wv * 16 + qd4 * 4 + r;
                hstage[b * 32 + jh * 16 + l15] = (signed char)hc;
            }

        // ---- publish h[t+1]: tagged 16B store -> drain -> atomic flag release ----
        // (hstage rows are wave-private: intra-wave LDS dep, no __syncthreads)
        {
            u64 codes = *(const u64*)(hstage + tid * 8);    // = hstage[pb*32 + psub*8]
            v4i sval = (v4i){(int)(codes & 0xffffffffu), (int)(codes >> 32), t + 1, 0};
            u64 pa = paddr_base + (u64)((t + 1) & 1) * 65536;
            asm volatile("global_store_dwordx4 %0, %1, off sc0 sc1\n\t"
                         "s_waitcnt vmcnt(0)"       // stores at coherence point (R7-verified)
                         :: "v"(pa), "v"(sval) : "memory");
            if (lane == 0)
                __hip_atomic_exchange(fwr + ((t + 1) & 1) * 64, (unsigned)(t + 1),
                                      __ATOMIC_RELAXED, __HIP_MEMORY_SCOPE_SYSTEM);
        }

        // ---- t+1 input-gate GEMM (hides peers' publish + flag flight) ----
        if (t + 1 < S_LEN) {
            v4i xfr[8];
            const signed char* xrow = x8 + (size_t)((t + 1) * BATCH + wv * 16 + l15) * 512 + qd4 * 16;
            #pragma unroll
            for (int k = 0; k < 8; k++) xfr[k] = *(const v4i*)(xrow + k * 64);
            #pragma unroll
            for (int nt = 0; nt < 8; nt++) {
                v4i a = (v4i){0, 0, 0, 0};
                #pragma unroll
                for (int k = 0; k < 8; k++) {
                    v4i bf = *(const v4i*)(wih_lds + (nt * 16 + l15) * 528 + k * 64 + qd4 * 16);
                    a = __builtin_amdgcn_mfma_i32_16x16x64_i8(xfr[k], bf, a, 0, 0, 0);
                }
                xacc[nt] = a;
            }
        }
    }
}

// ---------------- final FC: out[1,64,2] = h_T @ fc_q^T (exact int dot) ----------
// h[512] lives in slot 0 (tagged units); read codes via relaxed agent atomics
// (bypass possibly-stale cached zero lines from the in-graph memset).
__global__ void k_fc(const signed char* __restrict__ h8, const signed char* __restrict__ fc8,
                     const unsigned* __restrict__ mx_fc, float* __restrict__ out) {
    int tid = threadIdx.x;              // 128 threads = 64 b * 2 o
    int b = tid >> 1, o = tid & 1;
    const signed char* hp = h8 + b * 1024;          // 64 units * 16B per batch row
    const char4* wp = (const char4*)(fc8 + o * 512);
    int s = 0;
    for (int i = 0; i < 64; i++) {
        u64 hv = __hip_atomic_load((const u64*)(hp + i * 16), __ATOMIC_RELAXED, __HIP_MEMORY_SCOPE_AGENT);
        char4 w0 = wp[i * 2], w1 = wp[i * 2 + 1];
        signed char hb[8];
        *(u64*)hb = hv;
        s += hb[0] * w0.x + hb[1] * w0.y + hb[2] * w0.z + hb[3] * w0.w
           + hb[4] * w1.x + hb[5] * w1.y + hb[6] * w1.z + hb[7] * w1.w;
    }
    float sc = ldexpf(1.0f, scale_exp(__uint_as_float(*mx_fc)) - 4);
    out[b * 2 + o] = (float)s * sc;     // exact: s < 2^23, pow2 scale
}

extern "C" void kernel_launch(void* const* d_in, const int* in_sizes, int n_in,
                              void* d_out, int out_size, void* d_ws, size_t ws_size,
                              hipStream_t stream) {
    (void)in_sizes; (void)n_in; (void)out_size; (void)ws_size;
    const int*   text = (const int*)d_in[0];
    const float* emb  = (const float*)d_in[2];
    const float* w_ih = (const float*)d_in[3];
    const float* w_hh = (const float*)d_in[4];
    const float* b_ih = (const float*)d_in[5];
    const float* b_hh = (const float*)d_in[6];
    const float* fc_w = (const float*)d_in[7];

    char* ws = (char*)d_ws;
    unsigned*    flg  = (unsigned*)(ws + O_FLG);
    unsigned*    mx   = (unsigned*)(ws + O_MAX);
    signed char* h8   = (signed char*)(ws + O_H8);
    signed char* fc8  = (signed char*)(ws + O_FC8);
    signed char* wih8 = (signed char*)(ws + O_WIH8);
    signed char* whh8 = (signed char*)(ws + O_WHH8);
    signed char* x8   = (signed char*)(ws + O_X8);

    // zero flags + maxabs + BOTH tagged h slots
    // (flags=0 & tags=0 == step-0 sentinel; h0=0 codes)
    hipMemsetAsync(d_ws, 0, O_H8 + 2 * 65536, stream);

    k_maxabs<<<2048, 256, 0, stream>>>(emb, VOCAB * E_DIM, mx + 0);
    k_maxabs<<<256, 256, 0, stream>>>(w_ih, G4 * E_DIM, mx + 1);
    k_maxabs<<<256, 256, 0, stream>>>(w_hh, G4 * H_DIM, mx + 2);
    k_maxabs<<<1, 256, 0, stream>>>(fc_w, 2 * H_DIM, mx + 3);

    k_quantw<<<512, 256, 0, stream>>>(w_ih, G4 * E_DIM, mx + 1, wih8);
    k_quantw<<<512, 256, 0, stream>>>(w_hh, G4 * H_DIM, mx + 2, whh8);
    k_quantw<<<2, 256, 0, stream>>>(fc_w, 2 * H_DIM, mx + 3, fc8);

    k_embed<<<BATCH * S_LEN, 128, 0, stream>>>(emb, text, mx + 0, x8);

    k_lstm<<<NWG, 256, 0, stream>>>(wih8, whh8, x8, b_ih, b_hh, mx, h8, flg);

    k_fc<<<1, 128, 0, stream>>>(h8, fc8, mx + 3, (float*)d_out);
}